// Round 1
// baseline (862.295 us; speedup 1.0000x reference)
//
#include <hip/hip_runtime.h>
#include <hip/hip_bf16.h>
#include <stdint.h>

// Problem constants
#define NATOMS 32768
#define DDIM   1024
#define HDIM   1024
#define ENUM   4
#define MCAP   (NATOMS + ENUM * 128)   // 33280 = 260 * 128 (worst-case padded M)

typedef unsigned short u16;
typedef __attribute__((ext_vector_type(8))) __bf16 bf16x8;
typedef __attribute__((ext_vector_type(4))) float  f32x4;

// ---- workspace layout (bytes) ----
// Xp  : [MCAP][1024] bf16  (also reused as h2 output of GEMM2)
// H1  : [MCAP][1024] bf16
// W1T : [E][1024][1024] bf16 (transposed: [n][k])
// W2T : [E][1024][1024] bf16
// perm: [MCAP] int
// meta: [16] int  (0..3 counts, 4..7 cursors, 8..12 offs[0..4])
static const size_t XP_OFF   = 0;
static const size_t H1_OFF   = XP_OFF  + (size_t)MCAP * 1024 * 2;
static const size_t W1T_OFF  = H1_OFF  + (size_t)MCAP * 1024 * 2;
static const size_t W2T_OFF  = W1T_OFF + (size_t)ENUM * 1024 * 1024 * 2;
static const size_t PERM_OFF = W2T_OFF + (size_t)ENUM * 1024 * 1024 * 2;
static const size_t META_OFF = PERM_OFF + (size_t)MCAP * 4;

__device__ __forceinline__ u16 f2bf(float f) {
    unsigned u = __float_as_uint(f);
    u += 0x7fffu + ((u >> 16) & 1u);   // round-to-nearest-even
    return (u16)(u >> 16);
}
__device__ __forceinline__ float bf2f(u16 h) {
    return __uint_as_float(((unsigned)h) << 16);
}

// ---------------- init: perm = -1, meta = 0, out = 0 ----------------
__global__ void k_init(int* __restrict__ perm, int* __restrict__ meta,
                       float* __restrict__ out) {
    int i = blockIdx.x * 256 + threadIdx.x;
    if (i < MCAP) perm[i] = -1;
    if (blockIdx.x == 0) {
        if (threadIdx.x < 16) meta[threadIdx.x] = 0;
        if (threadIdx.x == 0) out[0] = 0.0f;
    }
}

// ---------------- count atoms per expert ----------------
__global__ void k_count(const int* __restrict__ sym, int* __restrict__ meta) {
    int n = blockIdx.x * 256 + threadIdx.x;
    if (n < NATOMS) atomicAdd(&meta[sym[n]], 1);
}

// ---------------- padded segment offsets + cursors ----------------
__global__ void k_offsets(int* __restrict__ meta) {
    if (threadIdx.x == 0 && blockIdx.x == 0) {
        int off = 0;
        for (int e = 0; e < 4; ++e) {
            meta[8 + e] = off;   // segment start
            meta[4 + e] = off;   // scatter cursor
            off += (meta[e] + 127) & ~127;
        }
        meta[12] = off;          // Mpad
    }
}

// ---------------- scatter atom ids into padded segments ----------------
__global__ void k_scatter(const int* __restrict__ sym, int* __restrict__ meta,
                          int* __restrict__ perm) {
    int n = blockIdx.x * 256 + threadIdx.x;
    if (n < NATOMS) {
        int e = sym[n];
        int pos = atomicAdd(&meta[4 + e], 1);
        perm[pos] = n;
    }
}

// ---------------- features fp32 -> permuted bf16 (zeros for pad) ----------------
__global__ void k_convx(const float* __restrict__ F, const int* __restrict__ perm,
                        u16* __restrict__ Xp) {
    int g = blockIdx.x * 256 + threadIdx.x;    // chunk of 8 elements
    int slot = g >> 7, c = g & 127;
    int src = perm[slot];
    u16 o[8];
    if (src < 0) {
#pragma unroll
        for (int j = 0; j < 8; ++j) o[j] = 0;
    } else {
        const float* fp = F + (size_t)src * 1024 + c * 8;
#pragma unroll
        for (int j = 0; j < 8; ++j) o[j] = f2bf(fp[j]);
    }
    uint4 v;
    v.x = (unsigned)o[0] | ((unsigned)o[1] << 16);
    v.y = (unsigned)o[2] | ((unsigned)o[3] << 16);
    v.z = (unsigned)o[4] | ((unsigned)o[5] << 16);
    v.w = (unsigned)o[6] | ((unsigned)o[7] << 16);
    *(uint4*)(void*)(Xp + (size_t)g * 8) = v;
}

// ---------------- W [E][K][N] fp32 -> WT [E][N][K] bf16 ----------------
__global__ void k_transw(const float* __restrict__ W, u16* __restrict__ WT) {
    __shared__ u16 tile[64][66];   // pad to dodge LDS bank conflicts
    int e  = blockIdx.y;
    int tn = blockIdx.x & 15;      // n tile
    int tk = blockIdx.x >> 4;      // k tile
    const float* Wp = W  + (size_t)e * 1024 * 1024;
    u16*        WTp = WT + (size_t)e * 1024 * 1024;
    int c = threadIdx.x & 63, r0 = threadIdx.x >> 6;
#pragma unroll
    for (int i = 0; i < 16; ++i) {
        int r = r0 + i * 4;
        tile[r][c] = f2bf(Wp[(size_t)(tk * 64 + r) * 1024 + tn * 64 + c]);
    }
    __syncthreads();
#pragma unroll
    for (int i = 0; i < 16; ++i) {
        int r = r0 + i * 4;
        WTp[(size_t)(tn * 64 + r) * 1024 + tk * 64 + c] = tile[c][r];
    }
}

// ---------------- bf16 MFMA GEMM: C = relu(A * BT^T + bias), m97 structure ----------------
// A  [MCAP][1024] bf16 row-major, BT [E][1024][1024] bf16 [n][k], bias [E][1024] fp32
__global__ __launch_bounds__(256, 2)
void k_gemm(const u16* __restrict__ A, const u16* __restrict__ BT,
            const float* __restrict__ bias, u16* __restrict__ C,
            const int* __restrict__ offs) {
    __shared__ u16 As[128 * 64];
    __shared__ u16 Bs[128 * 64];

    const int bx = blockIdx.x;           // n tile (0..7)
    const int by = blockIdx.y;           // m tile (0..259)
    const int m0 = by * 128, n0 = bx * 128;
    int e = (m0 >= offs[1]) + (m0 >= offs[2]) + (m0 >= offs[3]);  // segment -> expert

    const int t = threadIdx.x;
    const int w = t >> 6, lane = t & 63;
    const int quad = lane >> 4, lr = lane & 15;
    const int wm = w & 1, wn = w >> 1;   // 2x2 waves, each 64x64

    const u16* Ag = A + (size_t)m0 * 1024;
    const u16* Bg = BT + (size_t)e * 1024 * 1024 + (size_t)n0 * 1024;

    const int srow = t >> 3;             // staging row within 32-row group
    const int scol = (t & 7) * 8;        // staging col (8 bf16 = 16B)

    f32x4 acc[4][4];
#pragma unroll
    for (int i = 0; i < 4; ++i)
#pragma unroll
        for (int j = 0; j < 4; ++j) acc[i][j] = (f32x4){0.f, 0.f, 0.f, 0.f};

    for (int kt = 0; kt < 1024 / 64; ++kt) {
        const int kb = kt * 64;
#pragma unroll
        for (int i = 0; i < 4; ++i) {
            int row = i * 32 + srow;
            __builtin_amdgcn_global_load_lds(
                (const void*)(Ag + (size_t)row * 1024 + kb + scol),
                (void*)(As + (i * 4 + w) * 512), 16, 0, 0);
        }
#pragma unroll
        for (int i = 0; i < 4; ++i) {
            int row = i * 32 + srow;
            __builtin_amdgcn_global_load_lds(
                (const void*)(Bg + (size_t)row * 1024 + kb + scol),
                (void*)(Bs + (i * 4 + w) * 512), 16, 0, 0);
        }
        __syncthreads();
#pragma unroll
        for (int kk = 0; kk < 2; ++kk) {
            bf16x8 a[4], b[4];
#pragma unroll
            for (int mi = 0; mi < 4; ++mi) {
                int m = wm * 64 + mi * 16 + lr;
                a[mi] = *(const bf16x8*)(const void*)(As + m * 64 + kk * 32 + quad * 8);
            }
#pragma unroll
            for (int ni = 0; ni < 4; ++ni) {
                int n = wn * 64 + ni * 16 + lr;
                b[ni] = *(const bf16x8*)(const void*)(Bs + n * 64 + kk * 32 + quad * 8);
            }
#pragma unroll
            for (int mi = 0; mi < 4; ++mi)
#pragma unroll
                for (int ni = 0; ni < 4; ++ni)
                    acc[mi][ni] = __builtin_amdgcn_mfma_f32_16x16x32_bf16(
                        a[mi], b[ni], acc[mi][ni], 0, 0, 0);
        }
        __syncthreads();
    }

    // epilogue: bias + relu + bf16 store.  C/D layout: col=lane&15, row=quad*4+reg
#pragma unroll
    for (int ni = 0; ni < 4; ++ni) {
        int col = n0 + wn * 64 + ni * 16 + lr;
        float bv = bias[e * 1024 + col];
#pragma unroll
        for (int mi = 0; mi < 4; ++mi) {
            int rowb = m0 + wm * 64 + mi * 16 + quad * 4;
#pragma unroll
            for (int r = 0; r < 4; ++r) {
                float v = acc[mi][ni][r] + bv;
                v = v > 0.f ? v : 0.f;
                C[(size_t)(rowb + r) * 1024 + col] = f2bf(v);
            }
        }
    }
}

// ---------------- layer3 matvec + slope/intercept + global sum ----------------
__global__ __launch_bounds__(256)
void k_reduce(const u16* __restrict__ H2, const int* __restrict__ perm,
              const int* __restrict__ offs, const float* __restrict__ W3,
              const float* __restrict__ b3, const float* __restrict__ slope,
              const float* __restrict__ inter, float* __restrict__ out) {
    int w = threadIdx.x >> 6, lane = threadIdx.x & 63;
    int waveId = blockIdx.x * 4 + w;
    float acc = 0.f;
#pragma unroll 1
    for (int s = 0; s < 8; ++s) {
        int slot = waveId * 8 + s;
        if (slot >= MCAP) break;
        if (perm[slot] < 0) continue;     // wave-uniform branch
        int e = (slot >= offs[1]) + (slot >= offs[2]) + (slot >= offs[3]);
        const uint4*  hb = (const uint4*)(const void*)(H2 + (size_t)slot * 1024);
        const f32x4* wb = (const f32x4*)(const void*)(W3 + e * 1024);
        float p = 0.f;
#pragma unroll
        for (int h = 0; h < 2; ++h) {
            uint4 hv = hb[lane * 2 + h];
            f32x4 w0 = wb[lane * 4 + h * 2];
            f32x4 w1 = wb[lane * 4 + h * 2 + 1];
            p += bf2f((u16)hv.x) * w0[0] + bf2f((u16)(hv.x >> 16)) * w0[1];
            p += bf2f((u16)hv.y) * w0[2] + bf2f((u16)(hv.y >> 16)) * w0[3];
            p += bf2f((u16)hv.z) * w1[0] + bf2f((u16)(hv.z >> 16)) * w1[1];
            p += bf2f((u16)hv.w) * w1[2] + bf2f((u16)(hv.w >> 16)) * w1[3];
        }
        acc += slope[e] * p;
        if (lane == 0) acc += slope[e] * b3[e] + inter[e];   // + slope*b3 + intercept
    }
#pragma unroll
    for (int o = 32; o; o >>= 1) acc += __shfl_xor(acc, o, 64);
    if (lane == 0) atomicAdd(out, acc);
}

extern "C" void kernel_launch(void* const* d_in, const int* in_sizes, int n_in,
                              void* d_out, int out_size, void* d_ws, size_t ws_size,
                              hipStream_t stream) {
    const float* features = (const float*)d_in[0];
    const int*   sym      = (const int*)d_in[1];
    const float* W1       = (const float*)d_in[2];
    const float* b1       = (const float*)d_in[3];
    const float* W2       = (const float*)d_in[4];
    const float* b2       = (const float*)d_in[5];
    const float* W3       = (const float*)d_in[6];
    const float* b3       = (const float*)d_in[7];
    const float* slope    = (const float*)d_in[8];
    const float* inter    = (const float*)d_in[9];
    float* out = (float*)d_out;

    char* ws  = (char*)d_ws;
    u16* Xp   = (u16*)(ws + XP_OFF);    // also h2
    u16* H1b  = (u16*)(ws + H1_OFF);
    u16* W1T  = (u16*)(ws + W1T_OFF);
    u16* W2T  = (u16*)(ws + W2T_OFF);
    int* perm = (int*)(ws + PERM_OFF);
    int* meta = (int*)(ws + META_OFF);

    k_init<<<MCAP / 256, 256, 0, stream>>>(perm, meta, out);
    k_count<<<NATOMS / 256, 256, 0, stream>>>(sym, meta);
    k_offsets<<<1, 64, 0, stream>>>(meta);
    k_scatter<<<NATOMS / 256, 256, 0, stream>>>(sym, meta, perm);
    k_convx<<<(MCAP * 128) / 256, 256, 0, stream>>>(features, perm, Xp);
    k_transw<<<dim3(256, 4), 256, 0, stream>>>(W1, W1T);
    k_transw<<<dim3(256, 4), 256, 0, stream>>>(W2, W2T);
    k_gemm<<<dim3(8, 260), 256, 0, stream>>>(Xp, W1T, b1, H1b, meta + 8);
    k_gemm<<<dim3(8, 260), 256, 0, stream>>>(H1b, W2T, b2, Xp, meta + 8);
    k_reduce<<<MCAP / 32, 256, 0, stream>>>(Xp, perm, meta + 8, W3, b3, slope, inter, out);
}

// Round 2
// 535.027 us; speedup vs baseline: 1.6117x; 1.6117x over previous
//
#include <hip/hip_runtime.h>
#include <hip/hip_bf16.h>
#include <stdint.h>

// Problem constants
#define NATOMS 32768
#define DDIM   1024
#define HDIM   1024
#define ENUM   4
#define MCAP   (NATOMS + ENUM * 128)   // 33280 = 260 * 128 (worst-case padded M)

typedef unsigned short u16;
typedef __attribute__((ext_vector_type(8))) __bf16 bf16x8;
typedef __attribute__((ext_vector_type(4))) float  f32x4;

// ---- workspace layout (bytes) ----
// Xp  : [MCAP][1024] bf16  (also reused as h2 output of GEMM2)
// H1  : [MCAP][1024] bf16
// W1T : [E][1024][1024] bf16 (transposed: [n][k])
// W2T : [E][1024][1024] bf16
// perm: [MCAP] int
// meta: [256] int. Layout (ints):
//   count[e]  at e*16        (64-B line per counter -> no line ping-pong)
//   cursor[e] at 64 + e*16
//   offs[0..3] at 128..131, Mpad at 132
static const size_t XP_OFF   = 0;
static const size_t H1_OFF   = XP_OFF  + (size_t)MCAP * 1024 * 2;
static const size_t W1T_OFF  = H1_OFF  + (size_t)MCAP * 1024 * 2;
static const size_t W2T_OFF  = W1T_OFF + (size_t)ENUM * 1024 * 1024 * 2;
static const size_t PERM_OFF = W2T_OFF + (size_t)ENUM * 1024 * 1024 * 2;
static const size_t META_OFF = PERM_OFF + (size_t)MCAP * 4;

__device__ __forceinline__ u16 f2bf(float f) {
    unsigned u = __float_as_uint(f);
    u += 0x7fffu + ((u >> 16) & 1u);   // round-to-nearest-even
    return (u16)(u >> 16);
}
__device__ __forceinline__ float bf2f(u16 h) {
    return __uint_as_float(((unsigned)h) << 16);
}

// ---------------- init: perm = -1, meta = 0, out = 0 ----------------
__global__ void k_init(int* __restrict__ perm, int* __restrict__ meta,
                       float* __restrict__ out) {
    int i = blockIdx.x * 256 + threadIdx.x;
    if (i < MCAP) perm[i] = -1;
    if (blockIdx.x == 0) {
        if (threadIdx.x < 256) meta[threadIdx.x] = 0;
        if (threadIdx.x == 0) out[0] = 0.0f;
    }
}

// ---------------- count atoms per expert (wave-aggregated ballot) ----------------
__global__ void k_count(const int* __restrict__ sym, int* __restrict__ meta) {
    int n = blockIdx.x * 256 + threadIdx.x;
    int lane = threadIdx.x & 63;
    int e = sym[n];                    // NATOMS divisible by 256: no tail
#pragma unroll
    for (int j = 0; j < ENUM; ++j) {
        unsigned long long mask = __ballot(e == j);
        if (mask) {                    // wave-uniform
            int leader = __ffsll((long long)mask) - 1;
            if (lane == leader)
                atomicAdd(&meta[j * 16], __popcll(mask));
        }
    }
}

// ---------------- padded segment offsets + cursors ----------------
__global__ void k_offsets(int* __restrict__ meta) {
    if (threadIdx.x == 0 && blockIdx.x == 0) {
        int off = 0;
        for (int e = 0; e < 4; ++e) {
            meta[128 + e]    = off;    // segment start
            meta[64 + e*16]  = off;    // scatter cursor
            off += (meta[e * 16] + 127) & ~127;
        }
        meta[132] = off;               // Mpad
    }
}

// ---------------- scatter atom ids (wave-aggregated: 4 atomics/wave) ----------------
__global__ void k_scatter(const int* __restrict__ sym, int* __restrict__ meta,
                          int* __restrict__ perm) {
    int n = blockIdx.x * 256 + threadIdx.x;
    int lane = threadIdx.x & 63;
    int e = sym[n];
#pragma unroll
    for (int j = 0; j < ENUM; ++j) {
        unsigned long long mask = __ballot(e == j);
        if (mask) {                    // wave-uniform
            int leader = __ffsll((long long)mask) - 1;
            int base = 0;
            if (lane == leader)
                base = atomicAdd(&meta[64 + j * 16], __popcll(mask));
            base = __shfl(base, leader, 64);
            if (e == j) {
                int rank = __popcll(mask & ((1ull << lane) - 1ull));
                perm[base + rank] = n;
            }
        }
    }
}

// ---------------- features fp32 -> permuted bf16 (zeros for pad) ----------------
__global__ void k_convx(const float* __restrict__ F, const int* __restrict__ perm,
                        u16* __restrict__ Xp) {
    int g = blockIdx.x * 256 + threadIdx.x;    // chunk of 8 elements
    int slot = g >> 7, c = g & 127;
    int src = perm[slot];
    u16 o[8];
    if (src < 0) {
#pragma unroll
        for (int j = 0; j < 8; ++j) o[j] = 0;
    } else {
        const float* fp = F + (size_t)src * 1024 + c * 8;
#pragma unroll
        for (int j = 0; j < 8; ++j) o[j] = f2bf(fp[j]);
    }
    uint4 v;
    v.x = (unsigned)o[0] | ((unsigned)o[1] << 16);
    v.y = (unsigned)o[2] | ((unsigned)o[3] << 16);
    v.z = (unsigned)o[4] | ((unsigned)o[5] << 16);
    v.w = (unsigned)o[6] | ((unsigned)o[7] << 16);
    *(uint4*)(void*)(Xp + (size_t)g * 8) = v;
}

// ---------------- W [E][K][N] fp32 -> WT [E][N][K] bf16 ----------------
__global__ void k_transw(const float* __restrict__ W, u16* __restrict__ WT) {
    __shared__ u16 tile[64][66];   // pad to dodge LDS bank conflicts
    int e  = blockIdx.y;
    int tn = blockIdx.x & 15;      // n tile
    int tk = blockIdx.x >> 4;      // k tile
    const float* Wp = W  + (size_t)e * 1024 * 1024;
    u16*        WTp = WT + (size_t)e * 1024 * 1024;
    int c = threadIdx.x & 63, r0 = threadIdx.x >> 6;
#pragma unroll
    for (int i = 0; i < 16; ++i) {
        int r = r0 + i * 4;
        tile[r][c] = f2bf(Wp[(size_t)(tk * 64 + r) * 1024 + tn * 64 + c]);
    }
    __syncthreads();
#pragma unroll
    for (int i = 0; i < 16; ++i) {
        int r = r0 + i * 4;
        WTp[(size_t)(tn * 64 + r) * 1024 + tk * 64 + c] = tile[c][r];
    }
}

// ---------------- bf16 MFMA GEMM: C = relu(A * BT^T + bias), m97 structure ----------------
// A  [MCAP][1024] bf16 row-major, BT [E][1024][1024] bf16 [n][k], bias [E][1024] fp32
__global__ __launch_bounds__(256, 2)
void k_gemm(const u16* __restrict__ A, const u16* __restrict__ BT,
            const float* __restrict__ bias, u16* __restrict__ C,
            const int* __restrict__ offs) {
    __shared__ u16 As[128 * 64];
    __shared__ u16 Bs[128 * 64];

    const int bx = blockIdx.x;           // n tile (0..7)
    const int by = blockIdx.y;           // m tile (0..259)
    const int m0 = by * 128, n0 = bx * 128;
    int e = (m0 >= offs[1]) + (m0 >= offs[2]) + (m0 >= offs[3]);  // segment -> expert

    const int t = threadIdx.x;
    const int w = t >> 6, lane = t & 63;
    const int quad = lane >> 4, lr = lane & 15;
    const int wm = w & 1, wn = w >> 1;   // 2x2 waves, each 64x64

    const u16* Ag = A + (size_t)m0 * 1024;
    const u16* Bg = BT + (size_t)e * 1024 * 1024 + (size_t)n0 * 1024;

    const int srow = t >> 3;             // staging row within 32-row group
    const int scol = (t & 7) * 8;        // staging col (8 bf16 = 16B)

    f32x4 acc[4][4];
#pragma unroll
    for (int i = 0; i < 4; ++i)
#pragma unroll
        for (int j = 0; j < 4; ++j) acc[i][j] = (f32x4){0.f, 0.f, 0.f, 0.f};

    for (int kt = 0; kt < 1024 / 64; ++kt) {
        const int kb = kt * 64;
#pragma unroll
        for (int i = 0; i < 4; ++i) {
            int row = i * 32 + srow;
            __builtin_amdgcn_global_load_lds(
                (const void*)(Ag + (size_t)row * 1024 + kb + scol),
                (void*)(As + (i * 4 + w) * 512), 16, 0, 0);
        }
#pragma unroll
        for (int i = 0; i < 4; ++i) {
            int row = i * 32 + srow;
            __builtin_amdgcn_global_load_lds(
                (const void*)(Bg + (size_t)row * 1024 + kb + scol),
                (void*)(Bs + (i * 4 + w) * 512), 16, 0, 0);
        }
        __syncthreads();
#pragma unroll
        for (int kk = 0; kk < 2; ++kk) {
            bf16x8 a[4], b[4];
#pragma unroll
            for (int mi = 0; mi < 4; ++mi) {
                int m = wm * 64 + mi * 16 + lr;
                a[mi] = *(const bf16x8*)(const void*)(As + m * 64 + kk * 32 + quad * 8);
            }
#pragma unroll
            for (int ni = 0; ni < 4; ++ni) {
                int n = wn * 64 + ni * 16 + lr;
                b[ni] = *(const bf16x8*)(const void*)(Bs + n * 64 + kk * 32 + quad * 8);
            }
#pragma unroll
            for (int mi = 0; mi < 4; ++mi)
#pragma unroll
                for (int ni = 0; ni < 4; ++ni)
                    acc[mi][ni] = __builtin_amdgcn_mfma_f32_16x16x32_bf16(
                        a[mi], b[ni], acc[mi][ni], 0, 0, 0);
        }
        __syncthreads();
    }

    // epilogue: bias + relu + bf16 store.  C/D layout: col=lane&15, row=quad*4+reg
#pragma unroll
    for (int ni = 0; ni < 4; ++ni) {
        int col = n0 + wn * 64 + ni * 16 + lr;
        float bv = bias[e * 1024 + col];
#pragma unroll
        for (int mi = 0; mi < 4; ++mi) {
            int rowb = m0 + wm * 64 + mi * 16 + quad * 4;
#pragma unroll
            for (int r = 0; r < 4; ++r) {
                float v = acc[mi][ni][r] + bv;
                v = v > 0.f ? v : 0.f;
                C[(size_t)(rowb + r) * 1024 + col] = f2bf(v);
            }
        }
    }
}

// ---------------- layer3 matvec + slope/intercept + global sum ----------------
__global__ __launch_bounds__(256)
void k_reduce(const u16* __restrict__ H2, const int* __restrict__ perm,
              const int* __restrict__ offs, const float* __restrict__ W3,
              const float* __restrict__ b3, const float* __restrict__ slope,
              const float* __restrict__ inter, float* __restrict__ out) {
    int w = threadIdx.x >> 6, lane = threadIdx.x & 63;
    int waveId = blockIdx.x * 4 + w;
    float acc = 0.f;
#pragma unroll 1
    for (int s = 0; s < 8; ++s) {
        int slot = waveId * 8 + s;
        if (slot >= MCAP) break;
        if (perm[slot] < 0) continue;     // wave-uniform branch
        int e = (slot >= offs[1]) + (slot >= offs[2]) + (slot >= offs[3]);
        const uint4*  hb = (const uint4*)(const void*)(H2 + (size_t)slot * 1024);
        const f32x4* wb = (const f32x4*)(const void*)(W3 + e * 1024);
        float p = 0.f;
#pragma unroll
        for (int h = 0; h < 2; ++h) {
            uint4 hv = hb[lane * 2 + h];
            f32x4 w0 = wb[lane * 4 + h * 2];
            f32x4 w1 = wb[lane * 4 + h * 2 + 1];
            p += bf2f((u16)hv.x) * w0[0] + bf2f((u16)(hv.x >> 16)) * w0[1];
            p += bf2f((u16)hv.y) * w0[2] + bf2f((u16)(hv.y >> 16)) * w0[3];
            p += bf2f((u16)hv.z) * w1[0] + bf2f((u16)(hv.z >> 16)) * w1[1];
            p += bf2f((u16)hv.w) * w1[2] + bf2f((u16)(hv.w >> 16)) * w1[3];
        }
        acc += slope[e] * p;
        if (lane == 0) acc += slope[e] * b3[e] + inter[e];   // + slope*b3 + intercept
    }
#pragma unroll
    for (int o = 32; o; o >>= 1) acc += __shfl_xor(acc, o, 64);
    if (lane == 0) atomicAdd(out, acc);
}

extern "C" void kernel_launch(void* const* d_in, const int* in_sizes, int n_in,
                              void* d_out, int out_size, void* d_ws, size_t ws_size,
                              hipStream_t stream) {
    const float* features = (const float*)d_in[0];
    const int*   sym      = (const int*)d_in[1];
    const float* W1       = (const float*)d_in[2];
    const float* b1       = (const float*)d_in[3];
    const float* W2       = (const float*)d_in[4];
    const float* b2       = (const float*)d_in[5];
    const float* W3       = (const float*)d_in[6];
    const float* b3       = (const float*)d_in[7];
    const float* slope    = (const float*)d_in[8];
    const float* inter    = (const float*)d_in[9];
    float* out = (float*)d_out;

    char* ws  = (char*)d_ws;
    u16* Xp   = (u16*)(ws + XP_OFF);    // also h2
    u16* H1b  = (u16*)(ws + H1_OFF);
    u16* W1T  = (u16*)(ws + W1T_OFF);
    u16* W2T  = (u16*)(ws + W2T_OFF);
    int* perm = (int*)(ws + PERM_OFF);
    int* meta = (int*)(ws + META_OFF);

    k_init<<<MCAP / 256, 256, 0, stream>>>(perm, meta, out);
    k_count<<<NATOMS / 256, 256, 0, stream>>>(sym, meta);
    k_offsets<<<1, 64, 0, stream>>>(meta);
    k_scatter<<<NATOMS / 256, 256, 0, stream>>>(sym, meta, perm);
    k_convx<<<(MCAP * 128) / 256, 256, 0, stream>>>(features, perm, Xp);
    k_transw<<<dim3(256, 4), 256, 0, stream>>>(W1, W1T);
    k_transw<<<dim3(256, 4), 256, 0, stream>>>(W2, W2T);
    k_gemm<<<dim3(8, 260), 256, 0, stream>>>(Xp, W1T, b1, H1b, meta + 128);
    k_gemm<<<dim3(8, 260), 256, 0, stream>>>(H1b, W2T, b2, Xp, meta + 128);
    k_reduce<<<MCAP / 32, 256, 0, stream>>>(Xp, perm, meta + 128, W3, b3, slope, inter, out);
}

// Round 3
// 484.368 us; speedup vs baseline: 1.7802x; 1.1046x over previous
//
#include <hip/hip_runtime.h>
#include <hip/hip_bf16.h>
#include <stdint.h>

// Problem constants
#define NATOMS 32768
#define DDIM   1024
#define HDIM   1024
#define ENUM   4
#define MCAP   (NATOMS + ENUM * 128)   // 33280 = 260 * 128 (worst-case padded M)
#define GS     544                     // LDS group stride (u16): 8 rows * 64 + 32 pad
                                       // breaks the 128-B row-stride bank alias

typedef unsigned short u16;
typedef __attribute__((ext_vector_type(8))) __bf16 bf16x8;
typedef __attribute__((ext_vector_type(4))) float  f32x4;

// ---- workspace layout (bytes) ----
static const size_t XP_OFF   = 0;
static const size_t H1_OFF   = XP_OFF  + (size_t)MCAP * 1024 * 2;
static const size_t W1T_OFF  = H1_OFF  + (size_t)MCAP * 1024 * 2;
static const size_t W2T_OFF  = W1T_OFF + (size_t)ENUM * 1024 * 1024 * 2;
static const size_t PERM_OFF = W2T_OFF + (size_t)ENUM * 1024 * 1024 * 2;
static const size_t META_OFF = PERM_OFF + (size_t)MCAP * 4;
// meta ints: count[e] at e*16; cursor[e] at 64+e*16; offs[0..3] at 128..131; Mpad at 132

__device__ __forceinline__ u16 f2bf(float f) {
    unsigned u = __float_as_uint(f);
    u += 0x7fffu + ((u >> 16) & 1u);   // round-to-nearest-even
    return (u16)(u >> 16);
}
__device__ __forceinline__ float bf2f(u16 h) {
    return __uint_as_float(((unsigned)h) << 16);
}

// ---------------- init: perm = -1, meta = 0, out = 0 ----------------
__global__ void k_init(int* __restrict__ perm, int* __restrict__ meta,
                       float* __restrict__ out) {
    int i = blockIdx.x * 256 + threadIdx.x;
    if (i < MCAP) perm[i] = -1;
    if (blockIdx.x == 0) {
        if (threadIdx.x < 256) meta[threadIdx.x] = 0;
        if (threadIdx.x == 0) out[0] = 0.0f;
    }
}

// ---------------- count atoms per expert (wave-aggregated ballot) ----------------
__global__ void k_count(const int* __restrict__ sym, int* __restrict__ meta) {
    int n = blockIdx.x * 256 + threadIdx.x;
    int lane = threadIdx.x & 63;
    int e = sym[n];
#pragma unroll
    for (int j = 0; j < ENUM; ++j) {
        unsigned long long mask = __ballot(e == j);
        if (mask) {
            int leader = __ffsll((long long)mask) - 1;
            if (lane == leader)
                atomicAdd(&meta[j * 16], __popcll(mask));
        }
    }
}

// ---------------- padded segment offsets + cursors ----------------
__global__ void k_offsets(int* __restrict__ meta) {
    if (threadIdx.x == 0 && blockIdx.x == 0) {
        int off = 0;
        for (int e = 0; e < 4; ++e) {
            meta[128 + e]    = off;
            meta[64 + e*16]  = off;
            off += (meta[e * 16] + 127) & ~127;
        }
        meta[132] = off;
    }
}

// ---------------- scatter atom ids (wave-aggregated: 4 atomics/wave) ----------------
__global__ void k_scatter(const int* __restrict__ sym, int* __restrict__ meta,
                          int* __restrict__ perm) {
    int n = blockIdx.x * 256 + threadIdx.x;
    int lane = threadIdx.x & 63;
    int e = sym[n];
#pragma unroll
    for (int j = 0; j < ENUM; ++j) {
        unsigned long long mask = __ballot(e == j);
        if (mask) {
            int leader = __ffsll((long long)mask) - 1;
            int base = 0;
            if (lane == leader)
                base = atomicAdd(&meta[64 + j * 16], __popcll(mask));
            base = __shfl(base, leader, 64);
            if (e == j) {
                int rank = __popcll(mask & ((1ull << lane) - 1ull));
                perm[base + rank] = n;
            }
        }
    }
}

// ---------------- features fp32 -> permuted bf16 (zeros for pad) ----------------
__global__ void k_convx(const float* __restrict__ F, const int* __restrict__ perm,
                        u16* __restrict__ Xp) {
    int g = blockIdx.x * 256 + threadIdx.x;    // chunk of 8 elements
    int slot = g >> 7, c = g & 127;
    int src = perm[slot];
    u16 o[8];
    if (src < 0) {
#pragma unroll
        for (int j = 0; j < 8; ++j) o[j] = 0;
    } else {
        const float* fp = F + (size_t)src * 1024 + c * 8;
#pragma unroll
        for (int j = 0; j < 8; ++j) o[j] = f2bf(fp[j]);
    }
    uint4 v;
    v.x = (unsigned)o[0] | ((unsigned)o[1] << 16);
    v.y = (unsigned)o[2] | ((unsigned)o[3] << 16);
    v.z = (unsigned)o[4] | ((unsigned)o[5] << 16);
    v.w = (unsigned)o[6] | ((unsigned)o[7] << 16);
    *(uint4*)(void*)(Xp + (size_t)g * 8) = v;
}

// ---------------- W [E][K][N] fp32 -> WT [E][N][K] bf16 (z: 0=W1,1=W2) ----------------
__global__ void k_transw(const float* __restrict__ W1, u16* __restrict__ W1T,
                         const float* __restrict__ W2, u16* __restrict__ W2T) {
    __shared__ u16 tile[64][66];
    const float* W  = blockIdx.z ? W2  : W1;
    u16*         WT = blockIdx.z ? W2T : W1T;
    int e  = blockIdx.y;
    int tn = blockIdx.x & 15;
    int tk = blockIdx.x >> 4;
    const float* Wp = W  + (size_t)e * 1024 * 1024;
    u16*        WTp = WT + (size_t)e * 1024 * 1024;
    int c = threadIdx.x & 63, r0 = threadIdx.x >> 6;
#pragma unroll
    for (int i = 0; i < 16; ++i) {
        int r = r0 + i * 4;
        tile[r][c] = f2bf(Wp[(size_t)(tk * 64 + r) * 1024 + tn * 64 + c]);
    }
    __syncthreads();
#pragma unroll
    for (int i = 0; i < 16; ++i) {
        int r = r0 + i * 4;
        WTp[(size_t)(tn * 64 + r) * 1024 + tk * 64 + c] = tile[c][r];
    }
}

// ---------------- bf16 MFMA GEMM: C = relu(A * BT^T + bias) ----------------
// LDS layout: 8-row groups at stride GS=544 u16 (64-B pad per group) so that the
// fragment ds_read_b128 covers all 8 16-B bank slots: slot=(4g+4kk+quad)%8.
__global__ __launch_bounds__(256, 4)
void k_gemm(const u16* __restrict__ A, const u16* __restrict__ BT,
            const float* __restrict__ bias, u16* __restrict__ C,
            const int* __restrict__ offs) {
    __shared__ u16 As[16 * GS];
    __shared__ u16 Bs[16 * GS];

    const int bx = blockIdx.x;           // n tile (0..7)
    const int by = blockIdx.y;           // m tile (0..259)
    const int m0 = by * 128, n0 = bx * 128;
    int e = (m0 >= offs[1]) + (m0 >= offs[2]) + (m0 >= offs[3]);

    const int t = threadIdx.x;
    const int w = t >> 6, lane = t & 63;
    const int quad = lane >> 4, lr = lane & 15;
    const int wm = w & 1, wn = w >> 1;   // 2x2 waves, each 64x64

    const u16* Ag = A + (size_t)m0 * 1024;
    const u16* Bg = BT + (size_t)e * 1024 * 1024 + (size_t)n0 * 1024;

    const int srow = t >> 3;             // staging row within 32-row group
    const int scol = (t & 7) * 8;        // staging col (8 bf16 = 16B)

    // fragment read offsets (u16 units): row m -> (m>>3)*GS + (m&7)*64
    const int aGrp = wm * 8 + (lr >> 3);         // + mi*2 later
    const int rowOff = (lr & 7) * 64 + quad * 8; // + kk*32 later

    f32x4 acc[4][4];
#pragma unroll
    for (int i = 0; i < 4; ++i)
#pragma unroll
        for (int j = 0; j < 4; ++j) acc[i][j] = (f32x4){0.f, 0.f, 0.f, 0.f};

    for (int kt = 0; kt < 1024 / 64; ++kt) {
        const int kb = kt * 64;
#pragma unroll
        for (int i = 0; i < 4; ++i) {
            int row = i * 32 + srow;
            __builtin_amdgcn_global_load_lds(
                (const void*)(Ag + (size_t)row * 1024 + kb + scol),
                (void*)(As + (i * 4 + w) * GS), 16, 0, 0);
        }
#pragma unroll
        for (int i = 0; i < 4; ++i) {
            int row = i * 32 + srow;
            __builtin_amdgcn_global_load_lds(
                (const void*)(Bg + (size_t)row * 1024 + kb + scol),
                (void*)(Bs + (i * 4 + w) * GS), 16, 0, 0);
        }
        __syncthreads();
#pragma unroll
        for (int kk = 0; kk < 2; ++kk) {
            bf16x8 a[4], b[4];
#pragma unroll
            for (int mi = 0; mi < 4; ++mi)
                a[mi] = *(const bf16x8*)(const void*)(
                    As + (aGrp + mi * 2) * GS + rowOff + kk * 32);
#pragma unroll
            for (int ni = 0; ni < 4; ++ni)
                b[ni] = *(const bf16x8*)(const void*)(
                    Bs + (wn * 8 + (lr >> 3) + ni * 2) * GS + rowOff + kk * 32);
#pragma unroll
            for (int mi = 0; mi < 4; ++mi)
#pragma unroll
                for (int ni = 0; ni < 4; ++ni)
                    acc[mi][ni] = __builtin_amdgcn_mfma_f32_16x16x32_bf16(
                        a[mi], b[ni], acc[mi][ni], 0, 0, 0);
        }
        __syncthreads();
    }

    // epilogue: bias + relu + bf16 store.  C/D layout: col=lane&15, row=quad*4+reg
#pragma unroll
    for (int ni = 0; ni < 4; ++ni) {
        int col = n0 + wn * 64 + ni * 16 + lr;
        float bv = bias[e * 1024 + col];
#pragma unroll
        for (int mi = 0; mi < 4; ++mi) {
            int rowb = m0 + wm * 64 + mi * 16 + quad * 4;
#pragma unroll
            for (int r = 0; r < 4; ++r) {
                float v = acc[mi][ni][r] + bv;
                v = v > 0.f ? v : 0.f;
                C[(size_t)(rowb + r) * 1024 + col] = f2bf(v);
            }
        }
    }
}

// ---------------- layer3 matvec + slope/intercept + global sum ----------------
// 64 slots/block, block-level LDS reduce -> 520 atomics total
__global__ __launch_bounds__(256)
void k_reduce(const u16* __restrict__ H2, const int* __restrict__ perm,
              const int* __restrict__ offs, const float* __restrict__ W3,
              const float* __restrict__ b3, const float* __restrict__ slope,
              const float* __restrict__ inter, float* __restrict__ out) {
    __shared__ float part[4];
    int w = threadIdx.x >> 6, lane = threadIdx.x & 63;
    int waveId = blockIdx.x * 4 + w;
    float acc = 0.f;
#pragma unroll 1
    for (int s = 0; s < 16; ++s) {
        int slot = waveId * 16 + s;
        if (perm[slot] < 0) continue;     // wave-uniform branch
        int e = (slot >= offs[1]) + (slot >= offs[2]) + (slot >= offs[3]);
        const uint4*  hb = (const uint4*)(const void*)(H2 + (size_t)slot * 1024);
        const f32x4* wb = (const f32x4*)(const void*)(W3 + e * 1024);
        float p = 0.f;
#pragma unroll
        for (int h = 0; h < 2; ++h) {
            uint4 hv = hb[lane * 2 + h];
            f32x4 w0 = wb[lane * 4 + h * 2];
            f32x4 w1 = wb[lane * 4 + h * 2 + 1];
            p += bf2f((u16)hv.x) * w0[0] + bf2f((u16)(hv.x >> 16)) * w0[1];
            p += bf2f((u16)hv.y) * w0[2] + bf2f((u16)(hv.y >> 16)) * w0[3];
            p += bf2f((u16)hv.z) * w1[0] + bf2f((u16)(hv.z >> 16)) * w1[1];
            p += bf2f((u16)hv.w) * w1[2] + bf2f((u16)(hv.w >> 16)) * w1[3];
        }
        acc += slope[e] * p;
        if (lane == 0) acc += slope[e] * b3[e] + inter[e];
    }
#pragma unroll
    for (int o = 32; o; o >>= 1) acc += __shfl_xor(acc, o, 64);
    if (lane == 0) part[w] = acc;
    __syncthreads();
    if (threadIdx.x == 0)
        atomicAdd(out, part[0] + part[1] + part[2] + part[3]);
}

extern "C" void kernel_launch(void* const* d_in, const int* in_sizes, int n_in,
                              void* d_out, int out_size, void* d_ws, size_t ws_size,
                              hipStream_t stream) {
    const float* features = (const float*)d_in[0];
    const int*   sym      = (const int*)d_in[1];
    const float* W1       = (const float*)d_in[2];
    const float* b1       = (const float*)d_in[3];
    const float* W2       = (const float*)d_in[4];
    const float* b2       = (const float*)d_in[5];
    const float* W3       = (const float*)d_in[6];
    const float* b3       = (const float*)d_in[7];
    const float* slope    = (const float*)d_in[8];
    const float* inter    = (const float*)d_in[9];
    float* out = (float*)d_out;

    char* ws  = (char*)d_ws;
    u16* Xp   = (u16*)(ws + XP_OFF);    // also h2
    u16* H1b  = (u16*)(ws + H1_OFF);
    u16* W1T  = (u16*)(ws + W1T_OFF);
    u16* W2T  = (u16*)(ws + W2T_OFF);
    int* perm = (int*)(ws + PERM_OFF);
    int* meta = (int*)(ws + META_OFF);

    k_init<<<MCAP / 256, 256, 0, stream>>>(perm, meta, out);
    k_count<<<NATOMS / 256, 256, 0, stream>>>(sym, meta);
    k_offsets<<<1, 64, 0, stream>>>(meta);
    k_scatter<<<NATOMS / 256, 256, 0, stream>>>(sym, meta, perm);
    k_convx<<<(MCAP * 128) / 256, 256, 0, stream>>>(features, perm, Xp);
    k_transw<<<dim3(256, 4, 2), 256, 0, stream>>>(W1, W1T, W2, W2T);
    k_gemm<<<dim3(8, 260), 256, 0, stream>>>(Xp, W1T, b1, H1b, meta + 128);
    k_gemm<<<dim3(8, 260), 256, 0, stream>>>(H1b, W2T, b2, Xp, meta + 128);
    k_reduce<<<MCAP / 64, 256, 0, stream>>>(Xp, perm, meta + 128, W3, b3, slope, inter, out);
}

// Round 5
// 448.196 us; speedup vs baseline: 1.9239x; 1.0807x over previous
//
#include <hip/hip_runtime.h>
#include <hip/hip_bf16.h>
#include <stdint.h>

// Problem constants
#define NATOMS 32768
#define DDIM   1024
#define HDIM   1024
#define ENUM   4
#define MCAP   (NATOMS + ENUM * 128)   // 33280 = 260 * 128 (worst-case padded M)
#define GS     512                     // LDS group stride (u16): 8 rows * 64
// Bank conflicts handled by XOR swizzle: global k-chunk j of row r stored at
// LDS chunk (j ^ r); per 8-lane ds_read_b128 phase banks = 4*(j^r) -> all distinct.

typedef unsigned short u16;
typedef __attribute__((ext_vector_type(8))) __bf16 bf16x8;
typedef __attribute__((ext_vector_type(4))) float  f32x4;

// ---- workspace layout (bytes) ----
static const size_t XP_OFF   = 0;
static const size_t H1_OFF   = XP_OFF  + (size_t)MCAP * 1024 * 2;
static const size_t W1T_OFF  = H1_OFF  + (size_t)MCAP * 1024 * 2;
static const size_t W2T_OFF  = W1T_OFF + (size_t)ENUM * 1024 * 1024 * 2;
static const size_t PERM_OFF = W2T_OFF + (size_t)ENUM * 1024 * 1024 * 2;
static const size_t META_OFF = PERM_OFF + (size_t)MCAP * 4;
// meta ints: count[e] at e*16; cursor[e] at 64+e*16; offs[0..3] at 128..131; Mpad at 132

__device__ __forceinline__ u16 f2bf(float f) {
    unsigned u = __float_as_uint(f);
    u += 0x7fffu + ((u >> 16) & 1u);   // round-to-nearest-even
    return (u16)(u >> 16);
}
__device__ __forceinline__ float bf2f(u16 h) {
    return __uint_as_float(((unsigned)h) << 16);
}

// ---------------- init: perm = -1, meta = 0, out = 0 ----------------
__global__ void k_init(int* __restrict__ perm, int* __restrict__ meta,
                       float* __restrict__ out) {
    int i = blockIdx.x * 256 + threadIdx.x;
    if (i < MCAP) perm[i] = -1;
    if (blockIdx.x == 0) {
        if (threadIdx.x < 256) meta[threadIdx.x] = 0;
        if (threadIdx.x == 0) out[0] = 0.0f;
    }
}

// ---------------- count atoms per expert (wave-aggregated ballot) ----------------
__global__ void k_count(const int* __restrict__ sym, int* __restrict__ meta) {
    int n = blockIdx.x * 256 + threadIdx.x;
    int lane = threadIdx.x & 63;
    int e = sym[n];
#pragma unroll
    for (int j = 0; j < ENUM; ++j) {
        unsigned long long mask = __ballot(e == j);
        if (mask) {
            int leader = __ffsll((long long)mask) - 1;
            if (lane == leader)
                atomicAdd(&meta[j * 16], __popcll(mask));
        }
    }
}

// ------- padded segment offsets + cursors + constant energy term -> out -------
__global__ void k_offsets(int* __restrict__ meta, const float* __restrict__ slope,
                          const float* __restrict__ b3, const float* __restrict__ inter,
                          float* __restrict__ out) {
    if (threadIdx.x == 0 && blockIdx.x == 0) {
        int off = 0;
        float c = 0.f;
        for (int e = 0; e < 4; ++e) {
            meta[128 + e]    = off;
            meta[64 + e*16]  = off;
            int cnt = meta[e * 16];
            c += (float)cnt * (slope[e] * b3[e] + inter[e]);
            off += (cnt + 127) & ~127;
        }
        meta[132] = off;
        out[0] = c;               // per-atom constant terms, summed
    }
}

// ---------------- scatter atom ids (wave-aggregated: 4 atomics/wave) ----------------
__global__ void k_scatter(const int* __restrict__ sym, int* __restrict__ meta,
                          int* __restrict__ perm) {
    int n = blockIdx.x * 256 + threadIdx.x;
    int lane = threadIdx.x & 63;
    int e = sym[n];
#pragma unroll
    for (int j = 0; j < ENUM; ++j) {
        unsigned long long mask = __ballot(e == j);
        if (mask) {
            int leader = __ffsll((long long)mask) - 1;
            int base = 0;
            if (lane == leader)
                base = atomicAdd(&meta[64 + j * 16], __popcll(mask));
            base = __shfl(base, leader, 64);
            if (e == j) {
                int rank = __popcll(mask & ((1ull << lane) - 1ull));
                perm[base + rank] = n;
            }
        }
    }
}

// ---------------- features fp32 -> permuted bf16 (zeros for pad) ----------------
__global__ void k_convx(const float* __restrict__ F, const int* __restrict__ perm,
                        u16* __restrict__ Xp) {
    int g = blockIdx.x * 256 + threadIdx.x;    // chunk of 8 elements
    int slot = g >> 7, c = g & 127;
    int src = perm[slot];
    u16 o[8];
    if (src < 0) {
#pragma unroll
        for (int j = 0; j < 8; ++j) o[j] = 0;
    } else {
        const float* fp = F + (size_t)src * 1024 + c * 8;
#pragma unroll
        for (int j = 0; j < 8; ++j) o[j] = f2bf(fp[j]);
    }
    uint4 v;
    v.x = (unsigned)o[0] | ((unsigned)o[1] << 16);
    v.y = (unsigned)o[2] | ((unsigned)o[3] << 16);
    v.z = (unsigned)o[4] | ((unsigned)o[5] << 16);
    v.w = (unsigned)o[6] | ((unsigned)o[7] << 16);
    *(uint4*)(void*)(Xp + (size_t)g * 8) = v;
}

// ---------------- W [E][K][N] fp32 -> WT [E][N][K] bf16 (z: 0=W1,1=W2) ----------------
__global__ void k_transw(const float* __restrict__ W1, u16* __restrict__ W1T,
                         const float* __restrict__ W2, u16* __restrict__ W2T) {
    __shared__ u16 tile[64][66];
    const float* W  = blockIdx.z ? W2  : W1;
    u16*         WT = blockIdx.z ? W2T : W1T;
    int e  = blockIdx.y;
    int tn = blockIdx.x & 15;
    int tk = blockIdx.x >> 4;
    const float* Wp = W  + (size_t)e * 1024 * 1024;
    u16*        WTp = WT + (size_t)e * 1024 * 1024;
    int c = threadIdx.x & 63, r0 = threadIdx.x >> 6;
#pragma unroll
    for (int i = 0; i < 16; ++i) {
        int r = r0 + i * 4;
        tile[r][c] = f2bf(Wp[(size_t)(tk * 64 + r) * 1024 + tn * 64 + c]);
    }
    __syncthreads();
#pragma unroll
    for (int i = 0; i < 16; ++i) {
        int r = r0 + i * 4;
        WTp[(size_t)(tn * 64 + r) * 1024 + tk * 64 + c] = tile[c][r];
    }
}

// ---------------- bf16 MFMA GEMM: relu(A * BT^T + bias) ----------------
// FUSE=false: store bf16 C.  FUSE=true: fold layer3 dot + slope + global sum.
template <bool FUSE>
__global__ __launch_bounds__(256, 4)
void k_gemm(const u16* __restrict__ A, const u16* __restrict__ BT,
            const float* __restrict__ bias, u16* __restrict__ C,
            const int* __restrict__ meta, const float* __restrict__ W3,
            const float* __restrict__ slope, float* __restrict__ out) {
    __shared__ u16 As[16 * GS];
    __shared__ u16 Bs[16 * GS];
    const int* offs = meta + 128;

    const int bx = blockIdx.x;           // n tile (0..7)
    const int by = blockIdx.y;           // m tile (0..259)
    const int m0 = by * 128, n0 = bx * 128;
    int e = (m0 >= offs[1]) + (m0 >= offs[2]) + (m0 >= offs[3]);

    const int t = threadIdx.x;
    const int w = t >> 6, lane = t & 63;
    const int quad = lane >> 4, lr = lane & 15;
    const int wm = w & 1, wn = w >> 1;   // 2x2 waves, each 64x64

    const u16* Ag = A + (size_t)m0 * 1024;
    const u16* Bg = BT + (size_t)e * 1024 * 1024 + (size_t)n0 * 1024;

    const int srow  = t >> 3;                       // staging row in 32-row group
    const int srL   = srow & 7;                     // row within LDS group
    const int scol  = ((t & 7) ^ srL) * 8;          // XOR-swizzled global chunk

    // fragment read: row m -> group (m>>3), r = m&7; chunk j read at (j^r)*8
    const int r    = lr & 7;
    const int aGrp = wm * 8 + (lr >> 3);
    const int bGrp = wn * 8 + (lr >> 3);

    f32x4 acc[4][4];
#pragma unroll
    for (int i = 0; i < 4; ++i)
#pragma unroll
        for (int j = 0; j < 4; ++j) acc[i][j] = (f32x4){0.f, 0.f, 0.f, 0.f};

    for (int kt = 0; kt < 1024 / 64; ++kt) {
        const int kb = kt * 64;
#pragma unroll
        for (int i = 0; i < 4; ++i) {
            int row = i * 32 + srow;
            __builtin_amdgcn_global_load_lds(
                (const void*)(Ag + (size_t)row * 1024 + kb + scol),
                (void*)(As + (i * 4 + w) * GS), 16, 0, 0);
        }
#pragma unroll
        for (int i = 0; i < 4; ++i) {
            int row = i * 32 + srow;
            __builtin_amdgcn_global_load_lds(
                (const void*)(Bg + (size_t)row * 1024 + kb + scol),
                (void*)(Bs + (i * 4 + w) * GS), 16, 0, 0);
        }
        __syncthreads();
#pragma unroll
        for (int kk = 0; kk < 2; ++kk) {
            const int cOff = (((quad | (kk << 2)) ^ r)) * 8 + r * 64;
            bf16x8 a[4], b[4];
#pragma unroll
            for (int mi = 0; mi < 4; ++mi)
                a[mi] = *(const bf16x8*)(const void*)(As + (aGrp + mi * 2) * GS + cOff);
#pragma unroll
            for (int ni = 0; ni < 4; ++ni)
                b[ni] = *(const bf16x8*)(const void*)(Bs + (bGrp + ni * 2) * GS + cOff);
#pragma unroll
            for (int mi = 0; mi < 4; ++mi)
#pragma unroll
                for (int ni = 0; ni < 4; ++ni)
                    acc[mi][ni] = __builtin_amdgcn_mfma_f32_16x16x32_bf16(
                        a[mi], b[ni], acc[mi][ni], 0, 0, 0);
        }
        __syncthreads();
    }

    // epilogue.  C/D layout: col=lane&15, row=quad*4+reg
    if (!FUSE) {
#pragma unroll
        for (int ni = 0; ni < 4; ++ni) {
            int col = n0 + wn * 64 + ni * 16 + lr;
            float bv = bias[e * 1024 + col];
#pragma unroll
            for (int mi = 0; mi < 4; ++mi) {
                int rowb = m0 + wm * 64 + mi * 16 + quad * 4;
#pragma unroll
                for (int rr = 0; rr < 4; ++rr) {
                    float v = acc[mi][ni][rr] + bv;
                    v = v > 0.f ? v : 0.f;
                    C[(size_t)(rowb + rr) * 1024 + col] = f2bf(v);
                }
            }
        }
    } else {
        const int segEnd = offs[e] + meta[e * 16];   // valid slots < segEnd
        const float se = slope[e];
        float psum = 0.f;
#pragma unroll
        for (int ni = 0; ni < 4; ++ni) {
            int col = n0 + wn * 64 + ni * 16 + lr;
            float bv  = bias[e * 1024 + col];
            float w3s = W3[e * 1024 + col] * se;
#pragma unroll
            for (int mi = 0; mi < 4; ++mi) {
                int rowb = m0 + wm * 64 + mi * 16 + quad * 4;
#pragma unroll
                for (int rr = 0; rr < 4; ++rr) {
                    float v = acc[mi][ni][rr] + bv;
                    v = v > 0.f ? v : 0.f;
                    psum += (rowb + rr < segEnd) ? v * w3s : 0.f;
                }
            }
        }
#pragma unroll
        for (int o = 32; o; o >>= 1) psum += __shfl_xor(psum, o, 64);
        float* red = (float*)As;    // safe: all LDS reads done (loop-final barrier)
        if (lane == 0) red[w] = psum;
        __syncthreads();
        if (t == 0) atomicAdd(out, red[0] + red[1] + red[2] + red[3]);
    }
}

extern "C" void kernel_launch(void* const* d_in, const int* in_sizes, int n_in,
                              void* d_out, int out_size, void* d_ws, size_t ws_size,
                              hipStream_t stream) {
    const float* features = (const float*)d_in[0];
    const int*   sym      = (const int*)d_in[1];
    const float* W1       = (const float*)d_in[2];
    const float* b1       = (const float*)d_in[3];
    const float* W2       = (const float*)d_in[4];
    const float* b2       = (const float*)d_in[5];
    const float* W3       = (const float*)d_in[6];
    const float* b3       = (const float*)d_in[7];
    const float* slope    = (const float*)d_in[8];
    const float* inter    = (const float*)d_in[9];
    float* out = (float*)d_out;

    char* ws  = (char*)d_ws;
    u16* Xp   = (u16*)(ws + XP_OFF);
    u16* H1b  = (u16*)(ws + H1_OFF);
    u16* W1T  = (u16*)(ws + W1T_OFF);
    u16* W2T  = (u16*)(ws + W2T_OFF);
    int* perm = (int*)(ws + PERM_OFF);
    int* meta = (int*)(ws + META_OFF);

    k_init<<<MCAP / 256, 256, 0, stream>>>(perm, meta, out);
    k_count<<<NATOMS / 256, 256, 0, stream>>>(sym, meta);
    k_offsets<<<1, 64, 0, stream>>>(meta, slope, b3, inter, out);
    k_scatter<<<NATOMS / 256, 256, 0, stream>>>(sym, meta, perm);
    k_convx<<<(MCAP * 128) / 256, 256, 0, stream>>>(features, perm, Xp);
    k_transw<<<dim3(256, 4, 2), 256, 0, stream>>>(W1, W1T, W2, W2T);
    k_gemm<false><<<dim3(8, 260), 256, 0, stream>>>(Xp, W1T, b1, H1b, meta,
                                                    nullptr, nullptr, nullptr);
    k_gemm<true><<<dim3(8, 260), 256, 0, stream>>>(H1b, W2T, b2, nullptr, meta,
                                                   W3, slope, out);
}

// Round 6
// 384.864 us; speedup vs baseline: 2.2405x; 1.1646x over previous
//
#include <hip/hip_runtime.h>
#include <hip/hip_bf16.h>
#include <stdint.h>

// Problem constants
#define NATOMS 32768
#define DDIM   1024
#define HDIM   1024
#define ENUM   4
#define MCAP   (NATOMS + ENUM * 128)   // 33280 = 260 * 128 (worst-case padded M)

typedef unsigned short u16;
typedef unsigned char  u8;
typedef __attribute__((ext_vector_type(8)))  int   i32x8;
typedef __attribute__((ext_vector_type(16))) float f32x16;
typedef __attribute__((ext_vector_type(4)))  float f32x4;

// ---- workspace layout (bytes) ----
// Xp  : [MCAP][1024] fp8 e4m3 (features, permuted)
// H1  : [MCAP][1024] fp8 e4m3
// W1T8/W2T8 : [E][1024][1024] fp8, stores 32*W transposed [n][k] (2^-5 via MX scale)
static const size_t XP_OFF   = 0;
static const size_t H1_OFF   = XP_OFF  + (size_t)MCAP * 1024;
static const size_t W1T_OFF  = H1_OFF  + (size_t)MCAP * 1024;
static const size_t W2T_OFF  = W1T_OFF + (size_t)ENUM * 1024 * 1024;
static const size_t PERM_OFF = W2T_OFF + (size_t)ENUM * 1024 * 1024;
static const size_t META_OFF = PERM_OFF + (size_t)MCAP * 4;
// meta ints: count[e] at e*16; cursor[e] at 64+e*16; offs[0..3] at 128..131; Mpad at 132

__device__ __forceinline__ u8 f2fp8(float x) {
    int w = __builtin_amdgcn_cvt_pk_fp8_f32(x, x, 0, false);
    return (u8)(w & 0xFF);
}

// ---------------- init: perm = -1, meta = 0, out = 0 ----------------
__global__ void k_init(int* __restrict__ perm, int* __restrict__ meta,
                       float* __restrict__ out) {
    int i = blockIdx.x * 256 + threadIdx.x;
    if (i < MCAP) perm[i] = -1;
    if (blockIdx.x == 0) {
        if (threadIdx.x < 256) meta[threadIdx.x] = 0;
        if (threadIdx.x == 0) out[0] = 0.0f;
    }
}

// ---------------- count atoms per expert (wave-aggregated ballot) ----------------
__global__ void k_count(const int* __restrict__ sym, int* __restrict__ meta) {
    int n = blockIdx.x * 256 + threadIdx.x;
    int lane = threadIdx.x & 63;
    int e = sym[n];
#pragma unroll
    for (int j = 0; j < ENUM; ++j) {
        unsigned long long mask = __ballot(e == j);
        if (mask) {
            int leader = __ffsll((long long)mask) - 1;
            if (lane == leader)
                atomicAdd(&meta[j * 16], __popcll(mask));
        }
    }
}

// ------- padded segment offsets + cursors + constant energy term -> out -------
__global__ void k_offsets(int* __restrict__ meta, const float* __restrict__ slope,
                          const float* __restrict__ b3, const float* __restrict__ inter,
                          float* __restrict__ out) {
    if (threadIdx.x == 0 && blockIdx.x == 0) {
        int off = 0;
        float c = 0.f;
        for (int e = 0; e < 4; ++e) {
            meta[128 + e]    = off;
            meta[64 + e*16]  = off;
            int cnt = meta[e * 16];
            c += (float)cnt * (slope[e] * b3[e] + inter[e]);
            off += (cnt + 127) & ~127;
        }
        meta[132] = off;
        out[0] = c;               // per-atom constant terms, summed
    }
}

// ---------------- scatter atom ids (wave-aggregated: 4 atomics/wave) ----------------
__global__ void k_scatter(const int* __restrict__ sym, int* __restrict__ meta,
                          int* __restrict__ perm) {
    int n = blockIdx.x * 256 + threadIdx.x;
    int lane = threadIdx.x & 63;
    int e = sym[n];
#pragma unroll
    for (int j = 0; j < ENUM; ++j) {
        unsigned long long mask = __ballot(e == j);
        if (mask) {
            int leader = __ffsll((long long)mask) - 1;
            int base = 0;
            if (lane == leader)
                base = atomicAdd(&meta[64 + j * 16], __popcll(mask));
            base = __shfl(base, leader, 64);
            if (e == j) {
                int rank = __popcll(mask & ((1ull << lane) - 1ull));
                perm[base + rank] = n;
            }
        }
    }
}

// ---------------- features fp32 -> permuted fp8 (zeros for pad) ----------------
__global__ void k_convx(const float* __restrict__ F, const int* __restrict__ perm,
                        u8* __restrict__ Xp) {
    int g = blockIdx.x * 256 + threadIdx.x;    // chunk of 8 elements
    int slot = g >> 7, c = g & 127;
    int src = perm[slot];
    uint2 v;
    if (src < 0) {
        v.x = 0u; v.y = 0u;
    } else {
        const float* fp = F + (size_t)src * 1024 + c * 8;
        int w0 = 0, w1 = 0;
        w0 = __builtin_amdgcn_cvt_pk_fp8_f32(fp[0], fp[1], w0, false);
        w0 = __builtin_amdgcn_cvt_pk_fp8_f32(fp[2], fp[3], w0, true);
        w1 = __builtin_amdgcn_cvt_pk_fp8_f32(fp[4], fp[5], w1, false);
        w1 = __builtin_amdgcn_cvt_pk_fp8_f32(fp[6], fp[7], w1, true);
        v.x = (unsigned)w0; v.y = (unsigned)w1;
    }
    *(uint2*)(void*)(Xp + (size_t)g * 8) = v;
}

// -------- W [E][K][N] fp32 -> WT [E][N][K] fp8 of 32*W (z: 0=W1,1=W2) --------
__global__ void k_transw(const float* __restrict__ W1, u8* __restrict__ W1T,
                         const float* __restrict__ W2, u8* __restrict__ W2T) {
    __shared__ u8 tile[64][65];
    const float* W  = blockIdx.z ? W2  : W1;
    u8*          WT = blockIdx.z ? W2T : W1T;
    int e  = blockIdx.y;
    int tn = blockIdx.x & 15;
    int tk = blockIdx.x >> 4;
    const float* Wp = W  + (size_t)e * 1024 * 1024;
    u8*         WTp = WT + (size_t)e * 1024 * 1024;
    int c = threadIdx.x & 63, r0 = threadIdx.x >> 6;
#pragma unroll
    for (int i = 0; i < 16; ++i) {
        int r = r0 + i * 4;
        tile[r][c] = f2fp8(32.0f * Wp[(size_t)(tk * 64 + r) * 1024 + tn * 64 + c]);
    }
    __syncthreads();
#pragma unroll
    for (int i = 0; i < 16; ++i) {
        int r = r0 + i * 4;
        WTp[(size_t)(tn * 64 + r) * 1024 + tk * 64 + c] = tile[c][r];
    }
}

// ---------------- MX-fp8 MFMA GEMM: relu(A * (32B)^T * 2^-5 + bias) ----------------
// mfma_scale_f32_32x32x64_f8f6f4, fmt fp8/fp8, A-scale 2^0 (0x7F), B-scale 2^-5 (0x7A).
// LDS: 128 rows x 64 B per matrix; 16-B chunks XOR-swizzled: chunk j of row r at
// slot j^(r&3) -> fragment reads are <=2-way bank-aliased (free).
// FUSE=false: store fp8 C.  FUSE=true: fold layer3 dot + slope + global sum.
template <bool FUSE>
__global__ __launch_bounds__(256, 4)
void k_gemm(const u8* __restrict__ A, const u8* __restrict__ BT,
            const float* __restrict__ bias, u8* __restrict__ C,
            const int* __restrict__ meta, const float* __restrict__ W3,
            const float* __restrict__ slope, float* __restrict__ out) {
    __shared__ u8 As[128 * 64];
    __shared__ u8 Bs[128 * 64];
    const int* offs = meta + 128;

    const int bx = blockIdx.x;           // n tile (0..7)
    const int by = blockIdx.y;           // m tile (0..259)
    const int m0 = by * 128, n0 = bx * 128;
    int e = (m0 >= offs[1]) + (m0 >= offs[2]) + (m0 >= offs[3]);

    const int t = threadIdx.x;
    const int w = t >> 6, lane = t & 63;
    const int l31 = lane & 31, khalf = lane >> 5;
    const int wm = w & 1, wn = w >> 1;   // 2x2 waves, each 64x64

    const u8* Ag = A + (size_t)m0 * 1024;
    const u8* Bg = BT + (size_t)e * 1024 * 1024 + (size_t)n0 * 1024;

    // staging: instr i in {0,1}: row = i*64 + (t>>2); global chunk XOR row&3
    const int srow   = t >> 2;                    // 0..63
    const int gchunk = (t & 3) ^ (srow & 3);      // swizzled 16-B chunk

    f32x16 acc[2][2] = {};

    for (int kt = 0; kt < 1024 / 64; ++kt) {
        const int kb = kt * 64;
#pragma unroll
        for (int i = 0; i < 2; ++i) {
            int row = i * 64 + srow;
            __builtin_amdgcn_global_load_lds(
                (const void*)(Ag + (size_t)row * 1024 + kb + gchunk * 16),
                (void*)(As + i * 4096 + w * 1024), 16, 0, 0);
        }
#pragma unroll
        for (int i = 0; i < 2; ++i) {
            int row = i * 64 + srow;
            __builtin_amdgcn_global_load_lds(
                (const void*)(Bg + (size_t)row * 1024 + kb + gchunk * 16),
                (void*)(Bs + i * 4096 + w * 1024), 16, 0, 0);
        }
        __syncthreads();

        i32x8 a[2], b[2];
#pragma unroll
        for (int mi = 0; mi < 2; ++mi) {
            int m = wm * 64 + mi * 32 + l31;
            const u8* base = As + m * 64 + ((khalf ^ ((m >> 1) & 1)) << 5);
            uint4 lo = *(const uint4*)(const void*)(base + ((m & 1) << 4));
            uint4 hi = *(const uint4*)(const void*)(base + (((m & 1) ^ 1) << 4));
            union { uint4 q[2]; i32x8 v; } u;
            u.q[0] = lo; u.q[1] = hi;
            a[mi] = u.v;
        }
#pragma unroll
        for (int ni = 0; ni < 2; ++ni) {
            int n = wn * 64 + ni * 32 + l31;
            const u8* base = Bs + n * 64 + ((khalf ^ ((n >> 1) & 1)) << 5);
            uint4 lo = *(const uint4*)(const void*)(base + ((n & 1) << 4));
            uint4 hi = *(const uint4*)(const void*)(base + (((n & 1) ^ 1) << 4));
            union { uint4 q[2]; i32x8 v; } u;
            u.q[0] = lo; u.q[1] = hi;
            b[ni] = u.v;
        }
#pragma unroll
        for (int mi = 0; mi < 2; ++mi)
#pragma unroll
            for (int ni = 0; ni < 2; ++ni)
                acc[mi][ni] = __builtin_amdgcn_mfma_scale_f32_32x32x64_f8f6f4(
                    a[mi], b[ni], acc[mi][ni],
                    0, 0,                       // cbsz=fp8(e4m3), blgp=fp8(e4m3)
                    0, 0x7F7F7F7F,              // A scale 2^0
                    0, 0x7A7A7A7A);             // B scale 2^-5 (undo 32*W)
        __syncthreads();
    }

    // epilogue.  32x32 C/D layout: col=lane&31, row=(reg&3)+8*(reg>>2)+4*(lane>>5)
    if (!FUSE) {
#pragma unroll
        for (int ni = 0; ni < 2; ++ni) {
            int col = n0 + wn * 64 + ni * 32 + l31;
            float bv = bias[e * 1024 + col];
#pragma unroll
            for (int mi = 0; mi < 2; ++mi) {
                int rowb = m0 + wm * 64 + mi * 32 + 4 * khalf;
#pragma unroll
                for (int reg = 0; reg < 16; ++reg) {
                    int rowg = rowb + (reg & 3) + 8 * (reg >> 2);
                    float v = acc[mi][ni][reg] + bv;
                    v = v > 0.f ? v : 0.f;
                    C[(size_t)rowg * 1024 + col] = f2fp8(v);
                }
            }
        }
    } else {
        const int segEnd = offs[e] + meta[e * 16];   // valid slots < segEnd
        const float se = slope[e];
        float psum = 0.f;
#pragma unroll
        for (int ni = 0; ni < 2; ++ni) {
            int col = n0 + wn * 64 + ni * 32 + l31;
            float bv  = bias[e * 1024 + col];
            float w3s = W3[e * 1024 + col] * se;
#pragma unroll
            for (int mi = 0; mi < 2; ++mi) {
                int rowb = m0 + wm * 64 + mi * 32 + 4 * khalf;
#pragma unroll
                for (int reg = 0; reg < 16; ++reg) {
                    int rowg = rowb + (reg & 3) + 8 * (reg >> 2);
                    float v = acc[mi][ni][reg] + bv;
                    v = v > 0.f ? v : 0.f;
                    psum += (rowg < segEnd) ? v * w3s : 0.f;
                }
            }
        }
#pragma unroll
        for (int o = 32; o; o >>= 1) psum += __shfl_xor(psum, o, 64);
        float* red = (float*)As;    // safe: all LDS reads done (loop-final barrier)
        if (lane == 0) red[w] = psum;
        __syncthreads();
        if (t == 0) atomicAdd(out, red[0] + red[1] + red[2] + red[3]);
    }
}

extern "C" void kernel_launch(void* const* d_in, const int* in_sizes, int n_in,
                              void* d_out, int out_size, void* d_ws, size_t ws_size,
                              hipStream_t stream) {
    const float* features = (const float*)d_in[0];
    const int*   sym      = (const int*)d_in[1];
    const float* W1       = (const float*)d_in[2];
    const float* b1       = (const float*)d_in[3];
    const float* W2       = (const float*)d_in[4];
    const float* b2       = (const float*)d_in[5];
    const float* W3       = (const float*)d_in[6];
    const float* b3       = (const float*)d_in[7];
    const float* slope    = (const float*)d_in[8];
    const float* inter    = (const float*)d_in[9];
    float* out = (float*)d_out;

    char* ws  = (char*)d_ws;
    u8*  Xp   = (u8*)(ws + XP_OFF);
    u8*  H1b  = (u8*)(ws + H1_OFF);
    u8*  W1T  = (u8*)(ws + W1T_OFF);
    u8*  W2T  = (u8*)(ws + W2T_OFF);
    int* perm = (int*)(ws + PERM_OFF);
    int* meta = (int*)(ws + META_OFF);

    k_init<<<MCAP / 256, 256, 0, stream>>>(perm, meta, out);
    k_count<<<NATOMS / 256, 256, 0, stream>>>(sym, meta);
    k_offsets<<<1, 64, 0, stream>>>(meta, slope, b3, inter, out);
    k_scatter<<<NATOMS / 256, 256, 0, stream>>>(sym, meta, perm);
    k_convx<<<(MCAP * 128) / 256, 256, 0, stream>>>(features, perm, Xp);
    k_transw<<<dim3(256, 4, 2), 256, 0, stream>>>(W1, W1T, W2, W2T);
    k_gemm<false><<<dim3(8, 260), 256, 0, stream>>>(Xp, W1T, b1, H1b, meta,
                                                    nullptr, nullptr, nullptr);
    k_gemm<true><<<dim3(8, 260), 256, 0, stream>>>(H1b, W2T, b2, nullptr, meta,
                                                   W3, slope, out);
}

// Round 7
// 355.838 us; speedup vs baseline: 2.4233x; 1.0816x over previous
//
#include <hip/hip_runtime.h>
#include <hip/hip_bf16.h>
#include <stdint.h>

// Problem constants
#define NATOMS 32768
#define DDIM   1024
#define HDIM   1024
#define ENUM   4
#define MCAP   (NATOMS + ENUM * 128)   // 33280 = 260 * 128 (worst-case padded M)
#define MTILES 260

typedef unsigned short u16;
typedef unsigned char  u8;
typedef __attribute__((ext_vector_type(8)))  int   i32x8;
typedef __attribute__((ext_vector_type(16))) float f32x16;
typedef __attribute__((ext_vector_type(4)))  float f32x4;

// ---- workspace layout (bytes) ----
static const size_t XP_OFF   = 0;
static const size_t H1_OFF   = XP_OFF  + (size_t)MCAP * 1024;
static const size_t W1T_OFF  = H1_OFF  + (size_t)MCAP * 1024;
static const size_t W2T_OFF  = W1T_OFF + (size_t)ENUM * 1024 * 1024;
static const size_t PERM_OFF = W2T_OFF + (size_t)ENUM * 1024 * 1024;
static const size_t META_OFF = PERM_OFF + (size_t)MCAP * 4;
// meta ints: count[e] at e*16; cursor[e] at 64+e*16; offs[0..3] at 128..131; Mpad at 132

__device__ __forceinline__ u8 f2fp8(float x) {
    int w = __builtin_amdgcn_cvt_pk_fp8_f32(x, x, 0, false);
    return (u8)(w & 0xFF);
}

// ---------------- init: perm = -1, meta = 0, out = 0 ----------------
__global__ void k_init(int* __restrict__ perm, int* __restrict__ meta,
                       float* __restrict__ out) {
    int i = blockIdx.x * 256 + threadIdx.x;
    if (i < MCAP) perm[i] = -1;
    if (blockIdx.x == 0) {
        if (threadIdx.x < 256) meta[threadIdx.x] = 0;
        if (threadIdx.x == 0) out[0] = 0.0f;
    }
}

// ---------------- count atoms per expert (wave-aggregated ballot) ----------------
__global__ void k_count(const int* __restrict__ sym, int* __restrict__ meta) {
    int n = blockIdx.x * 256 + threadIdx.x;
    int lane = threadIdx.x & 63;
    int e = sym[n];
#pragma unroll
    for (int j = 0; j < ENUM; ++j) {
        unsigned long long mask = __ballot(e == j);
        if (mask) {
            int leader = __ffsll((long long)mask) - 1;
            if (lane == leader)
                atomicAdd(&meta[j * 16], __popcll(mask));
        }
    }
}

// ------- padded segment offsets + cursors + constant energy term -> out -------
__global__ void k_offsets(int* __restrict__ meta, const float* __restrict__ slope,
                          const float* __restrict__ b3, const float* __restrict__ inter,
                          float* __restrict__ out) {
    if (threadIdx.x == 0 && blockIdx.x == 0) {
        int off = 0;
        float c = 0.f;
        for (int e = 0; e < 4; ++e) {
            meta[128 + e]    = off;
            meta[64 + e*16]  = off;
            int cnt = meta[e * 16];
            c += (float)cnt * (slope[e] * b3[e] + inter[e]);
            off += (cnt + 127) & ~127;
        }
        meta[132] = off;
        out[0] = c;               // per-atom constant terms, summed
    }
}

// ---------------- scatter atom ids (wave-aggregated: 4 atomics/wave) ----------------
__global__ void k_scatter(const int* __restrict__ sym, int* __restrict__ meta,
                          int* __restrict__ perm) {
    int n = blockIdx.x * 256 + threadIdx.x;
    int lane = threadIdx.x & 63;
    int e = sym[n];
#pragma unroll
    for (int j = 0; j < ENUM; ++j) {
        unsigned long long mask = __ballot(e == j);
        if (mask) {
            int leader = __ffsll((long long)mask) - 1;
            int base = 0;
            if (lane == leader)
                base = atomicAdd(&meta[64 + j * 16], __popcll(mask));
            base = __shfl(base, leader, 64);
            if (e == j) {
                int rank = __popcll(mask & ((1ull << lane) - 1ull));
                perm[base + rank] = n;
            }
        }
    }
}

// ---------------- features fp32 -> permuted fp8 (zeros for pad) ----------------
__global__ void k_convx(const float* __restrict__ F, const int* __restrict__ perm,
                        u8* __restrict__ Xp) {
    int g = blockIdx.x * 256 + threadIdx.x;    // chunk of 8 elements
    int slot = g >> 7, c = g & 127;
    int src = perm[slot];
    uint2 v;
    if (src < 0) {
        v.x = 0u; v.y = 0u;
    } else {
        const float* fp = F + (size_t)src * 1024 + c * 8;
        int w0 = 0, w1 = 0;
        w0 = __builtin_amdgcn_cvt_pk_fp8_f32(fp[0], fp[1], w0, false);
        w0 = __builtin_amdgcn_cvt_pk_fp8_f32(fp[2], fp[3], w0, true);
        w1 = __builtin_amdgcn_cvt_pk_fp8_f32(fp[4], fp[5], w1, false);
        w1 = __builtin_amdgcn_cvt_pk_fp8_f32(fp[6], fp[7], w1, true);
        v.x = (unsigned)w0; v.y = (unsigned)w1;
    }
    *(uint2*)(void*)(Xp + (size_t)g * 8) = v;
}

// -------- W [E][K][N] fp32 -> WT [E][N][K] fp8 of 32*W (z: 0=W1,1=W2) --------
__global__ void k_transw(const float* __restrict__ W1, u8* __restrict__ W1T,
                         const float* __restrict__ W2, u8* __restrict__ W2T) {
    __shared__ u8 tile[64][65];
    const float* W  = blockIdx.z ? W2  : W1;
    u8*          WT = blockIdx.z ? W2T : W1T;
    int e  = blockIdx.y;
    int tn = blockIdx.x & 15;
    int tk = blockIdx.x >> 4;
    const float* Wp = W  + (size_t)e * 1024 * 1024;
    u8*         WTp = WT + (size_t)e * 1024 * 1024;
    int c = threadIdx.x & 63, r0 = threadIdx.x >> 6;
#pragma unroll
    for (int i = 0; i < 16; ++i) {
        int r = r0 + i * 4;
        tile[r][c] = f2fp8(32.0f * Wp[(size_t)(tk * 64 + r) * 1024 + tn * 64 + c]);
    }
    __syncthreads();
#pragma unroll
    for (int i = 0; i < 16; ++i) {
        int r = r0 + i * 4;
        WTp[(size_t)(tn * 64 + r) * 1024 + tk * 64 + c] = tile[c][r];
    }
}

// ---------------- MX-fp8 MFMA GEMM: relu(A * (32B)^T * 2^-5 + bias) ----------------
// BK=128 (32 KB LDS), XCD-aware block swizzle: flat%8 picks the m-tile within a
// group of 8, so all 8 n-tiles of one m-tile land on one XCD -> A-panel L2 reuse.
// LDS swizzle: chunk c (16B) of row r holds global chunk c^(r&7) -> ds_read_b128
// fragment phases hit 8 distinct bank slots (conflict-free).
// FUSE=false: store fp8 C.  FUSE=true: fold layer3 dot + slope + global sum.
template <bool FUSE>
__global__ __launch_bounds__(256, 4)
void k_gemm(const u8* __restrict__ A, const u8* __restrict__ BT,
            const float* __restrict__ bias, u8* __restrict__ C,
            const int* __restrict__ meta, const float* __restrict__ W3,
            const float* __restrict__ slope, float* __restrict__ out) {
    __shared__ u8 As[128 * 128];
    __shared__ u8 Bs[128 * 128];
    const int* offs = meta + 128;

    // XCD-aware swizzle (grid = dim3(8, 264) -> flat 0..2111)
    const int flat = blockIdx.y * 8 + blockIdx.x;
    const int mt = (flat >> 6) * 8 + (flat & 7);   // m tile
    const int nt = (flat & 63) >> 3;               // n tile
    if (mt >= MTILES) return;
    const int m0 = mt * 128, n0 = nt * 128;
    int e = (m0 >= offs[1]) + (m0 >= offs[2]) + (m0 >= offs[3]);

    const int t = threadIdx.x;
    const int w = t >> 6, lane = t & 63;
    const int l31 = lane & 31, khalf = lane >> 5;
    const int wm = w & 1, wn = w >> 1;   // 2x2 waves, each 64x64

    const u8* Ag = A + (size_t)m0 * 1024;
    const u8* Bg = BT + (size_t)e * 1024 * 1024 + (size_t)n0 * 1024;

    // staging: per matrix 4 instrs; instr i covers rows i*32+(t>>3), chunk t&7
    const int srow   = t >> 3;                    // 0..31
    const int gchunk = (t & 7) ^ (srow & 7);      // swizzled global 16-B chunk

    f32x16 acc[2][2] = {};

    for (int kt = 0; kt < 1024 / 128; ++kt) {
        const int kb = kt * 128;
#pragma unroll
        for (int i = 0; i < 4; ++i) {
            int row = i * 32 + srow;
            __builtin_amdgcn_global_load_lds(
                (const void*)(Ag + (size_t)row * 1024 + kb + gchunk * 16),
                (void*)(As + i * 4096 + w * 1024), 16, 0, 0);
        }
#pragma unroll
        for (int i = 0; i < 4; ++i) {
            int row = i * 32 + srow;
            __builtin_amdgcn_global_load_lds(
                (const void*)(Bg + (size_t)row * 1024 + kb + gchunk * 16),
                (void*)(Bs + i * 4096 + w * 1024), 16, 0, 0);
        }
        __syncthreads();

#pragma unroll
        for (int kk = 0; kk < 2; ++kk) {
            const int c0 = 4 * kk + 2 * khalf;    // even
            i32x8 a[2], b[2];
#pragma unroll
            for (int mi = 0; mi < 2; ++mi) {
                int m = wm * 64 + mi * 32 + l31;
                const u8* base = As + m * 128;
                int lo = ((c0 ^ (m & 7)) << 4);
                uint4 q0 = *(const uint4*)(const void*)(base + lo);
                uint4 q1 = *(const uint4*)(const void*)(base + (lo ^ 16));
                union { uint4 q[2]; i32x8 v; } u;
                u.q[0] = q0; u.q[1] = q1;
                a[mi] = u.v;
            }
#pragma unroll
            for (int ni = 0; ni < 2; ++ni) {
                int n = wn * 64 + ni * 32 + l31;
                const u8* base = Bs + n * 128;
                int lo = ((c0 ^ (n & 7)) << 4);
                uint4 q0 = *(const uint4*)(const void*)(base + lo);
                uint4 q1 = *(const uint4*)(const void*)(base + (lo ^ 16));
                union { uint4 q[2]; i32x8 v; } u;
                u.q[0] = q0; u.q[1] = q1;
                b[ni] = u.v;
            }
#pragma unroll
            for (int mi = 0; mi < 2; ++mi)
#pragma unroll
                for (int ni = 0; ni < 2; ++ni)
                    acc[mi][ni] = __builtin_amdgcn_mfma_scale_f32_32x32x64_f8f6f4(
                        a[mi], b[ni], acc[mi][ni],
                        0, 0,                       // cbsz=fp8(e4m3), blgp=fp8(e4m3)
                        0, 0x7F7F7F7F,              // A scale 2^0
                        0, 0x7A7A7A7A);             // B scale 2^-5 (undo 32*W)
        }
        __syncthreads();
    }

    // epilogue.  32x32 C/D layout: col=lane&31, row=(reg&3)+8*(reg>>2)+4*(lane>>5)
    if (!FUSE) {
#pragma unroll
        for (int ni = 0; ni < 2; ++ni) {
            int col = n0 + wn * 64 + ni * 32 + l31;
            float bv = bias[e * 1024 + col];
#pragma unroll
            for (int mi = 0; mi < 2; ++mi) {
                int rowb = m0 + wm * 64 + mi * 32 + 4 * khalf;
#pragma unroll
                for (int reg = 0; reg < 16; ++reg) {
                    int rowg = rowb + (reg & 3) + 8 * (reg >> 2);
                    float v = acc[mi][ni][reg] + bv;
                    v = v > 0.f ? v : 0.f;
                    C[(size_t)rowg * 1024 + col] = f2fp8(v);
                }
            }
        }
    } else {
        const int segEnd = offs[e] + meta[e * 16];   // valid slots < segEnd
        const float se = slope[e];
        float psum = 0.f;
#pragma unroll
        for (int ni = 0; ni < 2; ++ni) {
            int col = n0 + wn * 64 + ni * 32 + l31;
            float bv  = bias[e * 1024 + col];
            float w3s = W3[e * 1024 + col] * se;
#pragma unroll
            for (int mi = 0; mi < 2; ++mi) {
                int rowb = m0 + wm * 64 + mi * 32 + 4 * khalf;
#pragma unroll
                for (int reg = 0; reg < 16; ++reg) {
                    int rowg = rowb + (reg & 3) + 8 * (reg >> 2);
                    float v = acc[mi][ni][reg] + bv;
                    v = v > 0.f ? v : 0.f;
                    psum += (rowg < segEnd) ? v * w3s : 0.f;
                }
            }
        }
#pragma unroll
        for (int o = 32; o; o >>= 1) psum += __shfl_xor(psum, o, 64);
        float* red = (float*)As;    // safe: all LDS reads done (loop-final barrier)
        if (lane == 0) red[w] = psum;
        __syncthreads();
        if (t == 0) atomicAdd(out, red[0] + red[1] + red[2] + red[3]);
    }
}

extern "C" void kernel_launch(void* const* d_in, const int* in_sizes, int n_in,
                              void* d_out, int out_size, void* d_ws, size_t ws_size,
                              hipStream_t stream) {
    const float* features = (const float*)d_in[0];
    const int*   sym      = (const int*)d_in[1];
    const float* W1       = (const float*)d_in[2];
    const float* b1       = (const float*)d_in[3];
    const float* W2       = (const float*)d_in[4];
    const float* b2       = (const float*)d_in[5];
    const float* W3       = (const float*)d_in[6];
    const float* b3       = (const float*)d_in[7];
    const float* slope    = (const float*)d_in[8];
    const float* inter    = (const float*)d_in[9];
    float* out = (float*)d_out;

    char* ws  = (char*)d_ws;
    u8*  Xp   = (u8*)(ws + XP_OFF);
    u8*  H1b  = (u8*)(ws + H1_OFF);
    u8*  W1T  = (u8*)(ws + W1T_OFF);
    u8*  W2T  = (u8*)(ws + W2T_OFF);
    int* perm = (int*)(ws + PERM_OFF);
    int* meta = (int*)(ws + META_OFF);

    k_init<<<MCAP / 256, 256, 0, stream>>>(perm, meta, out);
    k_count<<<NATOMS / 256, 256, 0, stream>>>(sym, meta);
    k_offsets<<<1, 64, 0, stream>>>(meta, slope, b3, inter, out);
    k_scatter<<<NATOMS / 256, 256, 0, stream>>>(sym, meta, perm);
    k_convx<<<(MCAP * 128) / 256, 256, 0, stream>>>(features, perm, Xp);
    k_transw<<<dim3(256, 4, 2), 256, 0, stream>>>(W1, W1T, W2, W2T);
    k_gemm<false><<<dim3(8, 264), 256, 0, stream>>>(Xp, W1T, b1, H1b, meta,
                                                    nullptr, nullptr, nullptr);
    k_gemm<true><<<dim3(8, 264), 256, 0, stream>>>(H1b, W2T, b2, nullptr, meta,
                                                   W3, slope, out);
}